// Round 11
// baseline (222.452 us; speedup 1.0000x reference)
//
#include <hip/hip_runtime.h>
#include <hip/hip_bf16.h>

#define NB 4096
#define NT 50
#define NH 128
#define NINT 4
#define ROWS 64  // batch rows per block

typedef float f32x4 __attribute__((ext_vector_type(4)));
typedef __bf16 bf16x8 __attribute__((ext_vector_type(8)));
typedef short short8 __attribute__((ext_vector_type(8)));

#define L2E 1.4426950408889634f

__device__ __forceinline__ float frcp(float x) { return __builtin_amdgcn_rcpf(x); }

// exp2(-x): v_exp_f32 computes 2^x; neg is a free src modifier.
__device__ __forceinline__ float exp2neg(float x) {
  float r;
  asm("v_exp_f32 %0, -%1" : "=v"(r) : "v"(x));
  return r;
}

__device__ __forceinline__ unsigned short bfbits(float f) {
  __bf16 b = (__bf16)f;  // native RTNE; pairs pack to v_cvt_pk_bf16_f32
  return __builtin_bit_cast(unsigned short, b);
}

// Grid: 256 blocks = NINT(4) * (NB/64).  Block: 768 threads = 12 waves, 1/CU
// -> 3 waves/SIMD (the only occupancy step reachable with a weight-resident
// design: 2 whole 512-thr blocks would need a 128-reg cap -> spill, R3-R5).
// CREW SPLIT: waves 0-7 compute (96-reg weights + hm + acc ~ 150 regs,
// fits the 170-reg cap of __launch_bounds__(768,3)); waves 8-11 stage x,
// convert to bf16, and compute the interest gate holding w_interest in 64
// PERSISTENT regs -- deleting R10's 128KB/step LDS wintl re-reads (the
// bank-conflict source) and taking gather latency off the compute waves.
// R9 LESSON: inline-asm v_mfma bypasses LLVM's MFMA hazard recognizer -> NaN;
// use the builtin only.
__global__ __launch_bounds__(768, 3)
void gru_fused(const int* __restrict__ inputs, const float* __restrict__ emb,
               const float* __restrict__ w_int, const float* __restrict__ w_ih,
               const float* __restrict__ w_hh, const float* __restrict__ b_ih,
               const float* __restrict__ b_hh, const float* __restrict__ h0,
               float* __restrict__ out) {
  __shared__ unsigned short xs[2][ROWS * NH];      // 32 KB x tile, bf16, swizzled
  __shared__ unsigned short hs[2][ROWS * NH];      // 32 KB h tile, bf16, swizzled
  __shared__ __align__(16) float gbuf[2][ROWS];    // 512 B gates, double-buffered
  __shared__ int idxs[NT * ROWS];                  // 12.8 KB token ids

  const int tid = threadIdx.x;
  const int bx = blockIdx.x;
  const int I = bx >> 6;          // interest 0..3
  const int R0 = (bx & 63) * ROWS;
  const int w = tid >> 6;         // wave 0..11
  const int lane = tid & 63;
  const int l15 = lane & 15;
  const int l4 = lane >> 4;

  // ---- token indices (all 768 threads) ----
  for (int e = tid; e < NT * ROWS; e += 768) {
    int t = e >> 6, r = e & (ROWS - 1);
    idxs[e] = inputs[(size_t)(R0 + r) * NT + t];
  }
  __syncthreads();

  if (w < 8) {
    // ================== COMPUTE CREW (waves 0-7) ==================
    const int col = w * 16 + l15;  // this lane's output column

    // persistent weight fragments (96 VGPR) + biases, PRE-SCALED so the MFMA
    // result is the exp2 argument: gates r,i: *log2e; gate n: *2*log2e.
    // B-operand of 16x16x32: lane holds col=(lane&15), k=(lane>>4)*8 + 0..7
    bf16x8 wih[3][4], whh[3][4];
    float biasRI[2], biasNI, biasNH;
    {
      const float gs[3] = {L2E, L2E, 2.0f * L2E};
      #pragma unroll
      for (int g = 0; g < 3; ++g) {
        int oc = g * NH + col;
        #pragma unroll
        for (int kk = 0; kk < 4; ++kk) {
          int k0 = kk * 32 + l4 * 8;
          const float* pi = w_ih + ((size_t)(I * 384 + oc) * NH + k0);
          const float* ph = w_hh + ((size_t)(I * 384 + oc) * NH + k0);
          bf16x8 si, sh;
          #pragma unroll
          for (int e = 0; e < 8; ++e) {
            si[e] = (__bf16)(pi[e] * gs[g]);
            sh[e] = (__bf16)(ph[e] * gs[g]);
          }
          wih[g][kk] = si;
          whh[g][kk] = sh;
        }
      }
      biasRI[0] = (b_ih[I * 384 + col] + b_hh[I * 384 + col]) * L2E;
      biasRI[1] = (b_ih[I * 384 + NH + col] + b_hh[I * 384 + NH + col]) * L2E;
      biasNI = b_ih[I * 384 + 2 * NH + col] * (2.0f * L2E);
      biasNH = b_hh[I * 384 + 2 * NH + col] * (2.0f * L2E);
    }

    // h0 master (fp32 regs) + initial bf16 LDS copy
    // C/D layout: col = lane&15, row = (lane>>4)*4 + reg
    float hm[4][4];
    #pragma unroll
    for (int m = 0; m < 4; ++m) {
      #pragma unroll
      for (int j = 0; j < 4; ++j) {
        int row = m * 16 + l4 * 4 + j;
        float v = h0[((size_t)I * NB + R0 + row) * NH + col];
        hm[m][j] = v;
        hs[0][(row * NH + col) ^ ((row & 7) << 3)] = bfbits(v);
      }
    }
    __syncthreads();  // staging crew has filled xs[0], gbuf[0]

    for (int t = 0; t < NT; ++t) {
      const int cur = t & 1, nxt = cur ^ 1;
      const unsigned short* hsc = hs[cur];
      const unsigned short* xsc = xs[cur];
      unsigned short* hsn = hs[nxt];

      #pragma unroll
      for (int m = 0; m < 4; ++m) {
        f32x4 aR = f32x4{biasRI[0], biasRI[0], biasRI[0], biasRI[0]};
        f32x4 aI = f32x4{biasRI[1], biasRI[1], biasRI[1], biasRI[1]};
        f32x4 aNI = f32x4{biasNI, biasNI, biasNI, biasNI};
        f32x4 aNH = f32x4{biasNH, biasNH, biasNH, biasNH};

        int arow = m * 16 + l15;
        int alin = arow * NH + l4 * 8;  // bits 3-4
        int sw2 = (arow & 7) << 3;      // bits 3-5
        __builtin_amdgcn_s_setprio(1);
        #pragma unroll
        for (int kk = 0; kk < 4; ++kk) {
          int e = (alin + kk * 32) ^ sw2;  // kk*32: bits 5-6, carry-free add; XOR full index
          bf16x8 ah = __builtin_bit_cast(bf16x8, *(const short8*)&hsc[e]);
          bf16x8 ax = __builtin_bit_cast(bf16x8, *(const short8*)&xsc[e]);
          aR = __builtin_amdgcn_mfma_f32_16x16x32_bf16(ax, wih[0][kk], aR, 0, 0, 0);
          aR = __builtin_amdgcn_mfma_f32_16x16x32_bf16(ah, whh[0][kk], aR, 0, 0, 0);
          aI = __builtin_amdgcn_mfma_f32_16x16x32_bf16(ax, wih[1][kk], aI, 0, 0, 0);
          aI = __builtin_amdgcn_mfma_f32_16x16x32_bf16(ah, whh[1][kk], aI, 0, 0, 0);
          aNI = __builtin_amdgcn_mfma_f32_16x16x32_bf16(ax, wih[2][kk], aNI, 0, 0, 0);
          aNH = __builtin_amdgcn_mfma_f32_16x16x32_bf16(ah, whh[2][kk], aNH, 0, 0, 0);
        }
        __builtin_amdgcn_s_setprio(0);

        const f32x4 gq = *(const f32x4*)&gbuf[cur][m * 16 + l4 * 4];
        #pragma unroll
        for (int j = 0; j < 4; ++j) {
          int row = m * 16 + l4 * 4 + j;
          float rg = frcp(1.0f + exp2neg(aR[j]));
          float ig = frcp(1.0f + exp2neg(aI[j]));
          float an = fmaf(rg, aNH[j], aNI[j]);
          float ng = fmaf(2.0f, frcp(1.0f + exp2neg(an)), -1.0f);
          float c = gq[j] * ig;  // gates pre-thresholded by staging crew
          float hy = fmaf(c, ng - hm[m][j], hm[m][j]);
          hm[m][j] = hy;
          hsn[(row * NH + col) ^ ((row & 7) << 3)] = bfbits(hy);
        }
      }
      __syncthreads();
    }

    // epilogue: out[b][I][h]
    #pragma unroll
    for (int m = 0; m < 4; ++m) {
      #pragma unroll
      for (int j = 0; j < 4; ++j) {
        int row = m * 16 + l4 * 4 + j;
        out[(size_t)(R0 + row) * (NINT * NH) + I * NH + col] = hm[m][j];
      }
    }
  } else {
    // ================== STAGING CREW (waves 8-11, 256 threads) ==================
    // 8 threads per row-pair: gp = segment (16 floats), rows gr and gr+32.
    const int stid = tid - 512;    // 0..255
    const int gr = stid >> 3;      // 0..31
    const int gp = stid & 7;       // 0..7

    // w_interest slice held PERSISTENTLY in 64 regs (4 interests x 4 float4)
    float4 wv[NINT][4];
    #pragma unroll
    for (int i = 0; i < NINT; ++i) {
      const float4* p = (const float4*)(w_int + i * NH + gp * 16);
      #pragma unroll
      for (int q = 0; q < 4; ++q) wv[i][q] = p[q];
    }

    // stage one row: gate dots (f32) + shuffle-reduce + softmax, cvt + store
    auto stage_row = [&](int buf, int r, float4 a, float4 b, float4 c, float4 e) {
      float d[NINT];
      #pragma unroll
      for (int i = 0; i < NINT; ++i) {
        d[i] = a.x * wv[i][0].x + a.y * wv[i][0].y + a.z * wv[i][0].z + a.w * wv[i][0].w +
               b.x * wv[i][1].x + b.y * wv[i][1].y + b.z * wv[i][1].z + b.w * wv[i][1].w +
               c.x * wv[i][2].x + c.y * wv[i][2].y + c.z * wv[i][2].z + c.w * wv[i][2].w +
               e.x * wv[i][3].x + e.y * wv[i][3].y + e.z * wv[i][3].z + e.w * wv[i][3].w;
      }
      #pragma unroll
      for (int off = 1; off < 8; off <<= 1) {
        #pragma unroll
        for (int i = 0; i < NINT; ++i) d[i] += __shfl_xor(d[i], off, 64);
      }
      if (gp == 0) {
        float sa = d[0] * 10.f, sb = d[1] * 10.f, sc = d[2] * 10.f, sd = d[3] * 10.f;
        float mx = fmaxf(fmaxf(sa, sb), fmaxf(sc, sd));
        float ea = __expf(sa - mx), eb = __expf(sb - mx), ec = __expf(sc - mx),
              ed = __expf(sd - mx);
        float sel = (I == 0) ? ea : (I == 1) ? eb : (I == 2) ? ec : ed;
        float gv = sel * frcp(ea + eb + ec + ed);
        gbuf[buf][r] = (gv > 0.01f) ? gv : 0.0f;
      }
      short8 s0, s1;
      s0[0] = bfbits(a.x); s0[1] = bfbits(a.y); s0[2] = bfbits(a.z); s0[3] = bfbits(a.w);
      s0[4] = bfbits(b.x); s0[5] = bfbits(b.y); s0[6] = bfbits(b.z); s0[7] = bfbits(b.w);
      s1[0] = bfbits(c.x); s1[1] = bfbits(c.y); s1[2] = bfbits(c.z); s1[3] = bfbits(c.w);
      s1[4] = bfbits(e.x); s1[5] = bfbits(e.y); s1[6] = bfbits(e.z); s1[7] = bfbits(e.w);
      int base = r * NH + gp * 16;
      int sw = (r & 7) << 3;
      *(short8*)&xs[buf][base ^ sw] = s0;
      *(short8*)&xs[buf][(base + 8) ^ sw] = s1;
    };

    // prologue: stage x(0) + g(0)
    {
      const float4* p0 = (const float4*)(emb + (size_t)idxs[gr] * NH + gp * 16);
      const float4* p1 = (const float4*)(emb + (size_t)idxs[gr + 32] * NH + gp * 16);
      float4 a0 = p0[0], b0 = p0[1], c0 = p0[2], d0 = p0[3];
      float4 a1 = p1[0], b1 = p1[1], c1 = p1[2], d1 = p1[3];
      stage_row(0, gr, a0, b0, c0, d0);
      stage_row(0, gr + 32, a1, b1, c1, d1);
    }
    __syncthreads();

    for (int t = 0; t < NT; ++t) {
      const int nxt = (t & 1) ^ 1;
      if (t + 1 < NT) {
        const float4* p0 =
            (const float4*)(emb + (size_t)idxs[(t + 1) * ROWS + gr] * NH + gp * 16);
        const float4* p1 =
            (const float4*)(emb + (size_t)idxs[(t + 1) * ROWS + gr + 32] * NH + gp * 16);
        float4 a0 = p0[0], b0 = p0[1], c0 = p0[2], d0 = p0[3];
        float4 a1 = p1[0], b1 = p1[1], c1 = p1[2], d1 = p1[3];
        stage_row(nxt, gr, a0, b0, c0, d0);
        stage_row(nxt, gr + 32, a1, b1, c1, d1);
      }
      __syncthreads();
    }
  }
}

extern "C" void kernel_launch(void* const* d_in, const int* in_sizes, int n_in,
                              void* d_out, int out_size, void* d_ws, size_t ws_size,
                              hipStream_t stream) {
  const int* inputs = (const int*)d_in[0];
  const float* emb = (const float*)d_in[1];
  const float* w_int = (const float*)d_in[2];
  const float* w_ih = (const float*)d_in[3];
  const float* w_hh = (const float*)d_in[4];
  const float* b_ih = (const float*)d_in[5];
  const float* b_hh = (const float*)d_in[6];
  const float* h0 = (const float*)d_in[7];
  float* out = (float*)d_out;

  dim3 grid(NINT * (NB / ROWS));  // 256 blocks, one per CU
  dim3 block(768);                // 12 waves: 8 compute + 4 staging
  gru_fused<<<grid, block, 0, stream>>>(inputs, emb, w_int, w_ih, w_hh, b_ih,
                                        b_hh, h0, out);
}

// Round 12
// 192.591 us; speedup vs baseline: 1.1550x; 1.1550x over previous
//
#include <hip/hip_runtime.h>
#include <hip/hip_bf16.h>

#define NB 4096
#define NT 50
#define NH 128
#define NINT 4
#define ROWS 64  // batch rows per block

typedef float f32x4 __attribute__((ext_vector_type(4)));
typedef __bf16 bf16x8 __attribute__((ext_vector_type(8)));
typedef short short8 __attribute__((ext_vector_type(8)));
typedef short short4s __attribute__((ext_vector_type(4)));

#define L2E 1.4426950408889634f

__device__ __forceinline__ float frcp(float x) { return __builtin_amdgcn_rcpf(x); }

// exp2(-x): v_exp_f32 computes 2^x; neg is a free src modifier.
__device__ __forceinline__ float exp2neg(float x) {
  float r;
  asm("v_exp_f32 %0, -%1" : "=v"(r) : "v"(x));
  return r;
}

__device__ __forceinline__ unsigned short bfbits(float f) {
  __bf16 b = (__bf16)f;  // native RTNE; pairs pack to v_cvt_pk_bf16_f32
  return __builtin_bit_cast(unsigned short, b);
}

// Grid: 256 blocks = NINT(4) * (NB/64).  Block: 512 threads = 8 waves, 1/CU.
// R12 = R10 skeleton (196us; R11 crew-split regressed: same busy cycles, more
// stall) + TRANSPOSED MFMA: mfma(W_frag, data_frag, acc).  A-frag and B-frag
// share the per-lane layout (idx&15, (idx>>4)*8+e), so register contents and
// every LDS read stay byte-identical; only the acc meaning flips to
// (oc=(lane>>4)*4+reg, row=lane&15).  Wins: h-writeback = 1 ds_write_b64 per
// m (was 16 swizzled ds_write_b16), bias init = vector copy, gall read 4->1,
// out store = float4.  Plus wintl bank-deswizzle (R10's 4-way conflict).
// R9 LESSON: inline-asm v_mfma bypasses the MFMA hazard recognizer -> NaN.
// R3-R5 LESSON: weight-resident design needs the (512,2) 256-reg budget.
__global__ __launch_bounds__(512, 2)
void gru_fused(const int* __restrict__ inputs, const float* __restrict__ emb,
               const float* __restrict__ w_int, const float* __restrict__ w_ih,
               const float* __restrict__ w_hh, const float* __restrict__ b_ih,
               const float* __restrict__ b_hh, const float* __restrict__ h0,
               float* __restrict__ out) {
  __shared__ unsigned short xs[2][ROWS * NH];  // 32 KB x tile, bf16, swizzled
  __shared__ unsigned short hs[2][ROWS * NH];  // 32 KB h tile, bf16, swizzled
  __shared__ float gbuf[2][ROWS];              // 512 B gates, double-buffered
  __shared__ float wintl[NINT][NH + 16];       // 2.3 KB w_interest, bank-spread
  __shared__ int idxs[NT * ROWS];              // 12.8 KB token ids

  const int tid = threadIdx.x;
  const int bx = blockIdx.x;
  const int I = bx >> 6;          // interest 0..3
  const int R0 = (bx & 63) * ROWS;
  const int w = tid >> 6;         // wave 0..7
  const int lane = tid & 63;
  const int l15 = lane & 15;
  const int l4 = lane >> 4;
  const int oc0 = w * 16 + l4 * 4;  // lane's first h-col (owns oc0..oc0+3)

  // staging/gather mapping: 8 threads per row, 16 floats (64B) each
  const int sr = tid >> 3;  // row 0..63
  const int sp = tid & 7;   // segment

  // ---- token indices + bank-spread w_interest ----
  for (int e = tid; e < NT * ROWS; e += 512) {
    int t = e >> 6, r = e & (ROWS - 1);
    idxs[e] = inputs[(size_t)(R0 + r) * NT + t];
  }
  {
    // segment s (16 floats) shifted by (s>>1)*4 floats: 8 segments land on 8
    // distinct 4-bank groups -> conflict-free float4 reads in gate_from
    int i = tid >> 7, f = tid & 127;
    wintl[i][f + ((f >> 5) << 2)] = w_int[tid];
  }
  __syncthreads();

  // gate-from-staged-x: dots vs w_int, 3-level shuffle over the 8-lane row
  // group, softmax+threshold at sp==0 -> gbuf[buf][sr].
  auto gate_from = [&](int buf, float4 a, float4 b, float4 c, float4 e) {
    const int wbase = sp * 16 + (sp >> 1) * 4;
    float d[NINT];
    #pragma unroll
    for (int i = 0; i < NINT; ++i) {
      const float4* wq = (const float4*)&wintl[i][wbase];
      float4 w0 = wq[0], w1 = wq[1], w2 = wq[2], w3 = wq[3];
      d[i] = a.x * w0.x + a.y * w0.y + a.z * w0.z + a.w * w0.w +
             b.x * w1.x + b.y * w1.y + b.z * w1.z + b.w * w1.w +
             c.x * w2.x + c.y * w2.y + c.z * w2.z + c.w * w2.w +
             e.x * w3.x + e.y * w3.y + e.z * w3.z + e.w * w3.w;
    }
    #pragma unroll
    for (int off = 1; off < 8; off <<= 1) {
      #pragma unroll
      for (int i = 0; i < NINT; ++i) d[i] += __shfl_xor(d[i], off, 64);
    }
    if (sp == 0) {
      float sa = d[0] * 10.f, sb = d[1] * 10.f, sc = d[2] * 10.f, sd = d[3] * 10.f;
      float mx = fmaxf(fmaxf(sa, sb), fmaxf(sc, sd));
      float ea = __expf(sa - mx), eb = __expf(sb - mx), ec = __expf(sc - mx),
            ed = __expf(sd - mx);
      float sel = (I == 0) ? ea : (I == 1) ? eb : (I == 2) ? ec : ed;
      float gv = sel * frcp(ea + eb + ec + ed);
      gbuf[buf][sr] = (gv > 0.01f) ? gv : 0.0f;
    }
  };

  // ---- persistent weight fragments (96 VGPR, now MFMA A-operands) + bias
  //      vectors, PRE-SCALED: gates r,i: *log2e; gate n: *2*log2e.
  //      A-frag: lane holds row(=oc_local)=lane&15, k=(lane>>4)*8 + 0..7
  //      -> same bytes as the old B-frag load.
  bf16x8 wih[3][4], whh[3][4];
  f32x4 bR, bI, bNI, bNH;  // per-j bias vectors (j indexes oc0+j)
  {
    const float gs[3] = {L2E, L2E, 2.0f * L2E};
    #pragma unroll
    for (int g = 0; g < 3; ++g) {
      int oc = g * NH + w * 16 + l15;
      #pragma unroll
      for (int kk = 0; kk < 4; ++kk) {
        int k0 = kk * 32 + l4 * 8;
        const float* pi = w_ih + ((size_t)(I * 384 + oc) * NH + k0);
        const float* ph = w_hh + ((size_t)(I * 384 + oc) * NH + k0);
        bf16x8 si, sh;
        #pragma unroll
        for (int e = 0; e < 8; ++e) {
          si[e] = (__bf16)(pi[e] * gs[g]);
          sh[e] = (__bf16)(ph[e] * gs[g]);
        }
        wih[g][kk] = si;
        whh[g][kk] = sh;
      }
    }
    #pragma unroll
    for (int j = 0; j < 4; ++j) {
      bR[j] = (b_ih[I * 384 + oc0 + j] + b_hh[I * 384 + oc0 + j]) * L2E;
      bI[j] = (b_ih[I * 384 + NH + oc0 + j] + b_hh[I * 384 + NH + oc0 + j]) * L2E;
      bNI[j] = b_ih[I * 384 + 2 * NH + oc0 + j] * (2.0f * L2E);
      bNH[j] = b_hh[I * 384 + 2 * NH + oc0 + j] * (2.0f * L2E);
    }
  }

  // ---- h0 master (fp32 regs) + initial bf16 LDS copy ----
  // Transposed D layout: row(batch) = m*16 + (lane&15), hcol = oc0 + j
  float hm[4][4];
  #pragma unroll
  for (int m = 0; m < 4; ++m) {
    int row = m * 16 + l15;
    short4s p;
    #pragma unroll
    for (int j = 0; j < 4; ++j) {
      float v = h0[((size_t)I * NB + R0 + row) * NH + oc0 + j];
      hm[m][j] = v;
      p[j] = (short)bfbits(v);
    }
    *(short4s*)&hs[0][(row * NH + oc0) ^ ((row & 7) << 3)] = p;
  }

  // ---- stage x(0) + gate g(0) ----
  {
    const float4* src = (const float4*)(emb + (size_t)idxs[sr] * NH + sp * 16);
    float4 v0 = src[0], v1 = src[1], v2 = src[2], v3 = src[3];
    short8 s0, s1;
    s0[0] = bfbits(v0.x); s0[1] = bfbits(v0.y); s0[2] = bfbits(v0.z); s0[3] = bfbits(v0.w);
    s0[4] = bfbits(v1.x); s0[5] = bfbits(v1.y); s0[6] = bfbits(v1.z); s0[7] = bfbits(v1.w);
    s1[0] = bfbits(v2.x); s1[1] = bfbits(v2.y); s1[2] = bfbits(v2.z); s1[3] = bfbits(v2.w);
    s1[4] = bfbits(v3.x); s1[5] = bfbits(v3.y); s1[6] = bfbits(v3.z); s1[7] = bfbits(v3.w);
    int base = sr * NH + sp * 16;
    int sw = (sr & 7) << 3;
    *(short8*)&xs[0][base ^ sw] = s0;
    *(short8*)&xs[0][(base + 8) ^ sw] = s1;
    gate_from(0, v0, v1, v2, v3);
  }
  __syncthreads();

  // ---- main recurrence ----
  for (int t = 0; t < NT; ++t) {
    const int cur = t & 1, nxt = cur ^ 1;
    const bool pf = (t + 1 < NT);

    // prefetch x(t+1) into regs; latency hides under the 96 MFMAs
    float4 v0, v1, v2, v3;
    if (pf) {
      const float4* src =
          (const float4*)(emb + (size_t)idxs[(t + 1) * ROWS + sr] * NH + sp * 16);
      v0 = src[0]; v1 = src[1]; v2 = src[2]; v3 = src[3];
    }

    const unsigned short* hsc = hs[cur];
    const unsigned short* xsc = xs[cur];
    unsigned short* hsn = hs[nxt];

    #pragma unroll
    for (int m = 0; m < 4; ++m) {
      f32x4 aR = bR, aI = bI, aNI = bNI, aNH = bNH;  // vector bias init

      int brow = m * 16 + l15;        // B-frag col = batch row
      int blin = brow * NH + l4 * 8;  // bits 3-4
      int sw2 = (brow & 7) << 3;      // bits 3-5
      __builtin_amdgcn_s_setprio(1);
      #pragma unroll
      for (int kk = 0; kk < 4; ++kk) {
        int e = (blin + kk * 32) ^ sw2;  // kk*32: bits 5-6, carry-free; XOR full index
        bf16x8 bh = __builtin_bit_cast(bf16x8, *(const short8*)&hsc[e]);
        bf16x8 bx = __builtin_bit_cast(bf16x8, *(const short8*)&xsc[e]);
        // TRANSPOSED: A = weights, B = data -> D[oc][row]
        aR = __builtin_amdgcn_mfma_f32_16x16x32_bf16(wih[0][kk], bx, aR, 0, 0, 0);
        aR = __builtin_amdgcn_mfma_f32_16x16x32_bf16(whh[0][kk], bh, aR, 0, 0, 0);
        aI = __builtin_amdgcn_mfma_f32_16x16x32_bf16(wih[1][kk], bx, aI, 0, 0, 0);
        aI = __builtin_amdgcn_mfma_f32_16x16x32_bf16(whh[1][kk], bh, aI, 0, 0, 0);
        aNI = __builtin_amdgcn_mfma_f32_16x16x32_bf16(wih[2][kk], bx, aNI, 0, 0, 0);
        aNH = __builtin_amdgcn_mfma_f32_16x16x32_bf16(whh[2][kk], bh, aNH, 0, 0, 0);
      }
      __builtin_amdgcn_s_setprio(0);

      const float gv = gbuf[cur][brow];  // one scalar per lane (row-indexed)
      short4s p;
      #pragma unroll
      for (int j = 0; j < 4; ++j) {
        float rg = frcp(1.0f + exp2neg(aR[j]));
        float ig = frcp(1.0f + exp2neg(aI[j]));
        float an = fmaf(rg, aNH[j], aNI[j]);
        float ng = fmaf(2.0f, frcp(1.0f + exp2neg(an)), -1.0f);
        float c = gv * ig;  // gv pre-thresholded
        float hy = fmaf(c, ng - hm[m][j], hm[m][j]);
        hm[m][j] = hy;
        p[j] = (short)bfbits(hy);
      }
      // packed h-writeback: 4 consecutive h-cols, one ds_write_b64
      *(short4s*)&hsn[(brow * NH + oc0) ^ sw2] = p;
    }

    if (pf) {
      short8 s0, s1;
      s0[0] = bfbits(v0.x); s0[1] = bfbits(v0.y); s0[2] = bfbits(v0.z); s0[3] = bfbits(v0.w);
      s0[4] = bfbits(v1.x); s0[5] = bfbits(v1.y); s0[6] = bfbits(v1.z); s0[7] = bfbits(v1.w);
      s1[0] = bfbits(v2.x); s1[1] = bfbits(v2.y); s1[2] = bfbits(v2.z); s1[3] = bfbits(v2.w);
      s1[4] = bfbits(v3.x); s1[5] = bfbits(v3.y); s1[6] = bfbits(v3.z); s1[7] = bfbits(v3.w);
      int base = sr * NH + sp * 16;
      int sw = (sr & 7) << 3;
      *(short8*)&xs[nxt][base ^ sw] = s0;
      *(short8*)&xs[nxt][(base + 8) ^ sw] = s1;
      gate_from(nxt, v0, v1, v2, v3);  // g(t+1) in the staging shadow
    }
    __syncthreads();
  }

  // ---- epilogue: out[b][I][h], float4 per m ----
  #pragma unroll
  for (int m = 0; m < 4; ++m) {
    int row = m * 16 + l15;
    f32x4 o;
    #pragma unroll
    for (int j = 0; j < 4; ++j) o[j] = hm[m][j];
    *(f32x4*)&out[(size_t)(R0 + row) * (NINT * NH) + I * NH + oc0] = o;
  }
}

extern "C" void kernel_launch(void* const* d_in, const int* in_sizes, int n_in,
                              void* d_out, int out_size, void* d_ws, size_t ws_size,
                              hipStream_t stream) {
  const int* inputs = (const int*)d_in[0];
  const float* emb = (const float*)d_in[1];
  const float* w_int = (const float*)d_in[2];
  const float* w_ih = (const float*)d_in[3];
  const float* w_hh = (const float*)d_in[4];
  const float* b_ih = (const float*)d_in[5];
  const float* b_hh = (const float*)d_in[6];
  const float* h0 = (const float*)d_in[7];
  float* out = (float*)d_out;

  dim3 grid(NINT * (NB / ROWS));  // 256 blocks, one per CU
  dim3 block(512);
  gru_fused<<<grid, block, 0, stream>>>(inputs, emb, w_int, w_ih, w_hh, b_ih,
                                        b_hh, h0, out);
}